// Round 6
// baseline (148.481 us; speedup 1.0000x reference)
//
#include <hip/hip_runtime.h>
#include <hip/hip_bf16.h>
#include <stdint.h>

#define BATCH 8192
#define IN    1024
#define OUTD  1024
#define PBASIS 8

typedef __attribute__((ext_vector_type(8))) short bf16x8;
typedef __attribute__((ext_vector_type(4))) float floatx4;

__device__ __forceinline__ unsigned short f2bf(float f) {
    union { float f; unsigned u; } v; v.f = f;
    unsigned u = v.u;
    u += 0x7fffu + ((u >> 16) & 1u);   // RNE; inputs finite randn
    return (unsigned short)(u >> 16);
}

__device__ __forceinline__ bf16x8 u4bf(uint4 v) {
    union { uint4 u; bf16x8 b; } x; x.u = v; return x.b;
}

// Fused prep: blocks [0,4096) convert x -> bf16 (8 elem/thread);
// blocks [4096,6144) compute w_eff = bf16(sum_p coef * w) (2 elem/thread).
__global__ void prep_kernel(const float* __restrict__ x,
                            const float* __restrict__ coef,
                            const float* __restrict__ w,
                            unsigned short* __restrict__ xb,
                            unsigned short* __restrict__ weff) {
    int b = blockIdx.x;
    int tid = threadIdx.x;
    if (b < 4096) {
        int idx = b * 256 + tid;
        const float4* p = (const float4*)(x + (size_t)idx * 8);
        float4 a = p[0], c = p[1];
        uint4 o;
        o.x = (unsigned)f2bf(a.x) | ((unsigned)f2bf(a.y) << 16);
        o.y = (unsigned)f2bf(a.z) | ((unsigned)f2bf(a.w) << 16);
        o.z = (unsigned)f2bf(c.x) | ((unsigned)f2bf(c.y) << 16);
        o.w = (unsigned)f2bf(c.z) | ((unsigned)f2bf(c.w) << 16);
        ((uint4*)xb)[idx] = o;
    } else {
        int idx = (b - 4096) * 256 + tid;   // element pair index
        size_t e0 = (size_t)idx * 2;
        const float4* c4 = (const float4*)(coef + e0 * PBASIS);
        float4 a = c4[0], bb = c4[1], c = c4[2], d = c4[3];
        float s0 = (a.x + a.y + a.z + a.w) + (bb.x + bb.y + bb.z + bb.w);
        float s1 = (c.x + c.y + c.z + c.w) + (d.x + d.y + d.z + d.w);
        float2 ww = ((const float2*)w)[idx];
        unsigned b0 = f2bf(s0 * ww.x);
        unsigned b1 = f2bf(s1 * ww.y);
        ((unsigned*)weff)[idx] = b0 | (b1 << 16);
    }
}

__device__ __forceinline__ void gload_lds16(const void* g, void* l) {
    __builtin_amdgcn_global_load_lds(
        (const __attribute__((address_space(1))) unsigned int*)g,
        (__attribute__((address_space(3))) unsigned int*)l,
        16, 0, 0);
}

#define BARRIER()  asm volatile("s_barrier" ::: "memory")
#define WAIT_V4()  asm volatile("s_waitcnt vmcnt(4) lgkmcnt(0)" ::: "memory")
#define WAIT_V0()  asm volatile("s_waitcnt vmcnt(0) lgkmcnt(0)" ::: "memory")

// C[m,n] = sum_k A[m,k]*B[n,k]; A=[8192,1024], B=[1024,1024] bf16, C f32.
// BM=256 x BN=128, BK=64, 512 threads = 8 waves (4M x 2N), per-wave 64x64.
//
// R6 structural change vs R2 (122.5us): B NEVER touches LDS. B-fragments
// are loaded global->VGPR in the exact MFMA lane pattern (for fixed
// (tn,kh) the 64 lanes (t,q) cover 16 rows x one full 64B segment each:
// fully line-coalesced, L1/L2-served since B = 2MB), prefetched one
// K-tile ahead into ping-pong named uint4 regs. This cuts per-K-tile LDS
// traffic 176KB -> 96KB (A ds_read 64KB + A stage-write 32KB), dropping
// LDS below the 1032-cyc MFMA floor (prev: LDS-bound at 1375-1540 cyc).
// A keeps the proven path: tri-buffered (3 x 32KB) linear-dest
// global_load_lds with pre-swizzled source column.
// vmcnt invariant (robust to compiler reordering within an iteration):
// end-of-iter vmcnt(4) retires everything issued in iters <= kt-1
// (the <=4 leftovers are always the newest, i.e. from iter kt), so
// A(kt+1) is landed; B-reg readiness is compiler-tracked. K-accumulation
// order identical to R2 => bit-identical C, absmax 0.25.
__global__ __launch_bounds__(512, 2) void gemm_bt(
        const unsigned short* __restrict__ A,
        const unsigned short* __restrict__ B,
        float* __restrict__ C) {
    constexpr int K = IN, BK = 64, NT = K / BK;   // 16 K-steps
    constexpr int ASTG = 32768;                   // 32 KB per A stage
    constexpr int ES = 132;                       // epilogue row stride (floats)
    __shared__ __align__(16) char smem[135168];   // 3 A-stages 96K | ebuf 132K
    float* ebuf = (float*)smem;

    const int tid  = threadIdx.x;
    const int bm   = blockIdx.x, bn = blockIdx.y;
    const int lane = tid & 63;
    const int wave = tid >> 6;     // 0..7
    const int wm   = wave >> 1;    // 0..3 along M
    const int wn   = wave & 1;     // 0..1 along N
    const int t    = lane & 15;    // M/N index within 16
    const int q    = lane >> 4;    // K-quad
    const int r8   = t & 7;        // XOR swizzle key

    // ---- A staging map: 4 chunks/thread/K-step ----
    // chunk g: row = g>>3 (0..255), c = g&7; LDS slot = g (linear, required
    // by global_load_lds); global source column = c ^ (row&7) (involution).
    int g0 = tid,         ra0 = g0 >> 3, ca0 = (g0 & 7) ^ (ra0 & 7);
    int g1 = 512 + tid,   ra1 = g1 >> 3, ca1 = (g1 & 7) ^ (ra1 & 7);
    int g2 = 1024 + tid,  ra2 = g2 >> 3, ca2 = (g2 & 7) ^ (ra2 & 7);
    int g3 = 1536 + tid,  ra3 = g3 >> 3, ca3 = (g3 & 7) ^ (ra3 & 7);

    const unsigned short* gA0 = A + (size_t)(bm * 256 + ra0) * K + ca0 * 8;
    const unsigned short* gA1 = A + (size_t)(bm * 256 + ra1) * K + ca1 * 8;
    const unsigned short* gA2 = A + (size_t)(bm * 256 + ra2) * K + ca2 * 8;
    const unsigned short* gA3 = A + (size_t)(bm * 256 + ra3) * K + ca3 * 8;

    const int dA0 = g0 * 16, dA1 = g1 * 16, dA2 = g2 * 16, dA3 = g3 * 16;

    // ---- A fragment byte offsets within a stage ----
    const int aO0 = ((wm * 64 + t) * 64 + ((0 + q) ^ r8) * 8) * 2;
    const int aO1 = ((wm * 64 + t) * 64 + ((4 + q) ^ r8) * 8) * 2;

    // ---- B direct-global fragment bases (per N-tile tn) ----
    // lane (t,q) reads B[bn*128 + wn*64 + tn*16 + t][kt*64 + kh*32 + q*8 ..+7]
    const unsigned short* gBt0 = B + (size_t)(bn * 128 + wn * 64 + 0 * 16 + t) * K + q * 8;
    const unsigned short* gBt1 = B + (size_t)(bn * 128 + wn * 64 + 1 * 16 + t) * K + q * 8;
    const unsigned short* gBt2 = B + (size_t)(bn * 128 + wn * 64 + 2 * 16 + t) * K + q * 8;
    const unsigned short* gBt3 = B + (size_t)(bn * 128 + wn * 64 + 3 * 16 + t) * K + q * 8;

    floatx4 acc[4][4];
#pragma unroll
    for (int i = 0; i < 4; ++i)
#pragma unroll
        for (int j = 0; j < 4; ++j)
            acc[i][j] = (floatx4){0.f, 0.f, 0.f, 0.f};

#define STAGE_A(sp, ko)                                             \
    {                                                               \
        gload_lds16(gA0 + (ko), (sp) + dA0);                        \
        gload_lds16(gA1 + (ko), (sp) + dA1);                        \
        gload_lds16(gA2 + (ko), (sp) + dA2);                        \
        gload_lds16(gA3 + (ko), (sp) + dA3);                        \
    }
#define LOADB(kt, d00, d01, d10, d11, d20, d21, d30, d31)           \
    {                                                               \
        d00 = *(const uint4*)(gBt0 + (kt) * 64);                    \
        d01 = *(const uint4*)(gBt0 + (kt) * 64 + 32);               \
        d10 = *(const uint4*)(gBt1 + (kt) * 64);                    \
        d11 = *(const uint4*)(gBt1 + (kt) * 64 + 32);               \
        d20 = *(const uint4*)(gBt2 + (kt) * 64);                    \
        d21 = *(const uint4*)(gBt2 + (kt) * 64 + 32);               \
        d30 = *(const uint4*)(gBt3 + (kt) * 64);                    \
        d31 = *(const uint4*)(gBt3 + (kt) * 64 + 32);               \
    }
// One k-slice: 4 A ds_read_b128 + 16 MFMA with 4 B regs.
#define PHASE(sb, aOff, B0, B1, B2, B3)                             \
    {                                                               \
        const char* ab = (const char*)(sb) + (aOff);                \
        bf16x8 a0 = *(const bf16x8*)(ab + 0 * 2048);                \
        bf16x8 a1 = *(const bf16x8*)(ab + 1 * 2048);                \
        bf16x8 a2 = *(const bf16x8*)(ab + 2 * 2048);                \
        bf16x8 a3 = *(const bf16x8*)(ab + 3 * 2048);                \
        bf16x8 av[4] = {a0, a1, a2, a3};                            \
        bf16x8 bv[4] = {u4bf(B0), u4bf(B1), u4bf(B2), u4bf(B3)};    \
        __builtin_amdgcn_s_setprio(1);                              \
        _Pragma("unroll")                                           \
        for (int i = 0; i < 4; ++i)                                 \
            _Pragma("unroll")                                       \
            for (int j = 0; j < 4; ++j)                             \
                acc[i][j] = __builtin_amdgcn_mfma_f32_16x16x32_bf16(\
                    av[i], bv[j], acc[i][j], 0, 0, 0);              \
        __builtin_amdgcn_s_setprio(0);                              \
    }

    uint4 cb00, cb01, cb10, cb11, cb20, cb21, cb30, cb31;
    uint4 nb00, nb01, nb10, nb11, nb20, nb21, nb30, nb31;

    // ---- prologue: stage A0,A1; load B0; full drain (once, cheap) ----
    STAGE_A(smem, 0);
    STAGE_A(smem + ASTG, BK);
    LOADB(0, cb00, cb01, cb10, cb11, cb20, cb21, cb30, cb31);
    WAIT_V0();
    BARRIER();

    // ---- main loop: 2x-unrolled ping-pong (kt = 0..13), peeled tail ----
    int c = 0;
    for (int it = 0; it < 7; ++it) {
        const int kt0 = 2 * it, kt1 = 2 * it + 1;
        {   // even step kt0: compute cb, load nb=B(kt0+1), stage A(kt0+2)
            char* sb = smem + c * ASTG;
            int s2 = c + 2; if (s2 >= 3) s2 -= 3;
            LOADB(kt0 + 1, nb00, nb01, nb10, nb11, nb20, nb21, nb30, nb31);
            STAGE_A(smem + s2 * ASTG, (kt0 + 2) * BK);
            PHASE(sb, aO0, cb00, cb10, cb20, cb30);
            PHASE(sb, aO1, cb01, cb11, cb21, cb31);
            WAIT_V4();
            BARRIER();
            ++c; if (c >= 3) c -= 3;
        }
        {   // odd step kt1: compute nb, load cb=B(kt1+1), stage A(kt1+2)
            char* sb = smem + c * ASTG;
            int s2 = c + 2; if (s2 >= 3) s2 -= 3;
            LOADB(kt1 + 1, cb00, cb01, cb10, cb11, cb20, cb21, cb30, cb31);
            STAGE_A(smem + s2 * ASTG, (kt1 + 2) * BK);
            PHASE(sb, aO0, nb00, nb10, nb20, nb30);
            PHASE(sb, aO1, nb01, nb11, nb21, nb31);
            WAIT_V4();
            BARRIER();
            ++c; if (c >= 3) c -= 3;
        }
    }
    {   // kt = 14 (even, cb): load nb=B(15); no A stage; drain
        char* sb = smem + c * ASTG;
        LOADB(15, nb00, nb01, nb10, nb11, nb20, nb21, nb30, nb31);
        PHASE(sb, aO0, cb00, cb10, cb20, cb30);
        PHASE(sb, aO1, cb01, cb11, cb21, cb31);
        WAIT_V0();
        BARRIER();
        ++c; if (c >= 3) c -= 3;
    }
    {   // kt = 15 (odd, nb): nothing to load
        char* sb = smem + c * ASTG;
        PHASE(sb, aO0, nb00, nb10, nb20, nb30);
        PHASE(sb, aO1, nb01, nb11, nb21, nb31);
        WAIT_V0();
        BARRIER();
    }
#undef PHASE
#undef LOADB
#undef STAGE_A

    __syncthreads();   // full drain before LDS reuse as ebuf

    // ---- epilogue: dump 256x128 f32 via LDS (ES=132 pad), float4 out ----
    // D layout: col = t, row = q*4 + r  [m89/m91 verified]
#pragma unroll
    for (int tm = 0; tm < 4; ++tm)
#pragma unroll
        for (int tn = 0; tn < 4; ++tn)
#pragma unroll
            for (int r = 0; r < 4; ++r)
                ebuf[(wm * 64 + tm * 16 + q * 4 + r) * ES
                     + wn * 64 + tn * 16 + t] = acc[tm][tn][r];
    __syncthreads();
#pragma unroll
    for (int ps = 0; ps < 16; ++ps) {
        int row  = ps * 16 + (tid >> 5);
        int col4 = tid & 31;
        float4 v = *(const float4*)(ebuf + row * ES + col4 * 4);
        *(float4*)(C + (size_t)(bm * 256 + row) * OUTD + bn * 128 + col4 * 4) = v;
    }
}

extern "C" void kernel_launch(void* const* d_in, const int* in_sizes, int n_in,
                              void* d_out, int out_size, void* d_ws, size_t ws_size,
                              hipStream_t stream) {
    const float* x    = (const float*)d_in[0];
    const float* coef = (const float*)d_in[1];
    const float* w    = (const float*)d_in[2];
    float* out = (float*)d_out;

    unsigned short* xb   = (unsigned short*)d_ws;                                   // 16 MB
    unsigned short* weff = (unsigned short*)((char*)d_ws + (size_t)BATCH * IN * 2); // +2 MB

    prep_kernel<<<6144, 256, 0, stream>>>(x, coef, w, xb, weff);
    gemm_bt<<<dim3(BATCH / 256, OUTD / 128), 512, 0, stream>>>(xb, weff, out);
}

// Round 7
// 125.635 us; speedup vs baseline: 1.1818x; 1.1818x over previous
//
#include <hip/hip_runtime.h>
#include <hip/hip_bf16.h>
#include <stdint.h>

#define BATCH 8192
#define IN    1024
#define OUTD  1024
#define PBASIS 8

typedef __attribute__((ext_vector_type(8))) short bf16x8;
typedef __attribute__((ext_vector_type(4))) float floatx4;

__device__ __forceinline__ unsigned short f2bf(float f) {
    union { float f; unsigned u; } v; v.f = f;
    unsigned u = v.u;
    u += 0x7fffu + ((u >> 16) & 1u);   // RNE; inputs finite randn
    return (unsigned short)(u >> 16);
}

// Fused prep: blocks [0,4096) convert x -> bf16 (8 elem/thread);
// blocks [4096,6144) compute w_eff = bf16(sum_p coef * w) (2 elem/thread).
__global__ void prep_kernel(const float* __restrict__ x,
                            const float* __restrict__ coef,
                            const float* __restrict__ w,
                            unsigned short* __restrict__ xb,
                            unsigned short* __restrict__ weff) {
    int b = blockIdx.x;
    int tid = threadIdx.x;
    if (b < 4096) {
        int idx = b * 256 + tid;
        const float4* p = (const float4*)(x + (size_t)idx * 8);
        float4 a = p[0], c = p[1];
        uint4 o;
        o.x = (unsigned)f2bf(a.x) | ((unsigned)f2bf(a.y) << 16);
        o.y = (unsigned)f2bf(a.z) | ((unsigned)f2bf(a.w) << 16);
        o.z = (unsigned)f2bf(c.x) | ((unsigned)f2bf(c.y) << 16);
        o.w = (unsigned)f2bf(c.z) | ((unsigned)f2bf(c.w) << 16);
        ((uint4*)xb)[idx] = o;
    } else {
        int idx = (b - 4096) * 256 + tid;   // element pair index
        size_t e0 = (size_t)idx * 2;
        const float4* c4 = (const float4*)(coef + e0 * PBASIS);
        float4 a = c4[0], bb = c4[1], c = c4[2], d = c4[3];
        float s0 = (a.x + a.y + a.z + a.w) + (bb.x + bb.y + bb.z + bb.w);
        float s1 = (c.x + c.y + c.z + c.w) + (d.x + d.y + d.z + d.w);
        float2 ww = ((const float2*)w)[idx];
        unsigned b0 = f2bf(s0 * ww.x);
        unsigned b1 = f2bf(s1 * ww.y);
        ((unsigned*)weff)[idx] = b0 | (b1 << 16);
    }
}

__device__ __forceinline__ void gload_lds16(const void* g, void* l) {
    __builtin_amdgcn_global_load_lds(
        (const __attribute__((address_space(1))) unsigned int*)g,
        (__attribute__((address_space(3))) unsigned int*)l,
        16, 0, 0);
}

// Raw barrier + counted waits (T3+T4): loads stay in flight across barriers.
#define BARRIER()  asm volatile("s_barrier" ::: "memory")
#define WAIT_V6L0() asm volatile("s_waitcnt vmcnt(6) lgkmcnt(0)" ::: "memory")
#define WAIT_V0L0() asm volatile("s_waitcnt vmcnt(0) lgkmcnt(0)" ::: "memory")

// C[m,n] = sum_k A[m,k]*B[n,k]; A=[8192,1024], B=[1024,1024] bf16, C f32.
//
// R7: SAME sync skeleton as R2 (passed twice; prologue 12 loads ->
// vmcnt(6); per K-tile {stage3 | phase | stage3 | phase -> vmcnt(6) ->
// barrier}; tail vmcnt(0)) but resized so the tri-buffer fits TWO
// blocks per CU: BM=128 x BN=64, BK=64, 256 threads = 4 waves (2M x 2N),
// per-wave 64x32 out. Stage = 24KB (A 16K + B 8K), tri-buffer 72KB ->
// 2 blocks/CU resident (144KB LDS). Grid 64x16 = 1024 blocks = 4/CU
// dispatched, 2 co-resident. Rationale (R6 counters): gemm was
// latency/barrier-stall-bound at 1 block/CU (MfmaUtil 12%, VALUBusy 6%,
// Occ 18.6%); cross-block overlap (m114) hides barrier drains that a
// single resident block exposes. Same 6-loads/iter -> identical vmcnt(6)
// invariant. Per-C-element K-accumulation order unchanged -> bit-identical.
__global__ __launch_bounds__(256, 2) void gemm_bt(
        const unsigned short* __restrict__ A,
        const unsigned short* __restrict__ B,
        float* __restrict__ C) {
    constexpr int K = IN, BK = 64, NT = K / BK;   // 16 K-steps
    constexpr int STG = 24576;                    // 24 KB per stage (A 16K + B 8K)
    constexpr int ES = 68;                        // epilogue row stride (floats)
    __shared__ __align__(16) char smem[3 * STG];  // 72 KiB
    float* ebuf = (float*)smem;                   // epilogue reuse (128*68*4 = 34.8K)

    const int tid  = threadIdx.x;
    const int bm   = blockIdx.x, bn = blockIdx.y;
    const int lane = tid & 63;
    const int wave = tid >> 6;     // 0..3
    const int wm   = wave >> 1;    // 0..1 along M
    const int wn   = wave & 1;     // 0..1 along N
    const int t    = lane & 15;    // M/N index within 16
    const int q    = lane >> 4;    // K-quad
    const int r8   = t & 7;        // XOR swizzle key

    // ---- staging map: 6 chunks/thread/K-step (A: 4, B: 2) ----
    // chunk g: row = g>>3, c = g&7; LDS slot = g (linear, required by
    // global_load_lds); global source column = c ^ (row&7) (involution).
    int g0 = tid,        ra0 = g0 >> 3, ca0 = (g0 & 7) ^ (ra0 & 7);
    int g1 = 256 + tid,  ra1 = g1 >> 3, ca1 = (g1 & 7) ^ (ra1 & 7);
    int g2 = 512 + tid,  ra2 = g2 >> 3, ca2 = (g2 & 7) ^ (ra2 & 7);
    int g3 = 768 + tid,  ra3 = g3 >> 3, ca3 = (g3 & 7) ^ (ra3 & 7);
    int h0 = tid,        rb0 = h0 >> 3, cb0 = (h0 & 7) ^ (rb0 & 7);
    int h1 = 256 + tid,  rb1 = h1 >> 3, cb1 = (h1 & 7) ^ (rb1 & 7);

    const unsigned short* gA0 = A + (size_t)(bm * 128 + ra0) * K + ca0 * 8;
    const unsigned short* gA1 = A + (size_t)(bm * 128 + ra1) * K + ca1 * 8;
    const unsigned short* gA2 = A + (size_t)(bm * 128 + ra2) * K + ca2 * 8;
    const unsigned short* gA3 = A + (size_t)(bm * 128 + ra3) * K + ca3 * 8;
    const unsigned short* gB0 = B + (size_t)(bn * 64 + rb0) * K + cb0 * 8;
    const unsigned short* gB1 = B + (size_t)(bn * 64 + rb1) * K + cb1 * 8;

    const int dA0 = g0 * 16, dA1 = g1 * 16, dA2 = g2 * 16, dA3 = g3 * 16;
    const int dB0 = 16384 + h0 * 16, dB1 = 16384 + h1 * 16;

    // ---- fragment byte offsets within a stage (A at 0, B at 16384) ----
    const int aO0 = ((wm * 64 + t) * 64 + ((0 + q) ^ r8) * 8) * 2;
    const int aO1 = ((wm * 64 + t) * 64 + ((4 + q) ^ r8) * 8) * 2;
    const int bO0 = 16384 + ((wn * 32 + t) * 64 + ((0 + q) ^ r8) * 8) * 2;
    const int bO1 = 16384 + ((wn * 32 + t) * 64 + ((4 + q) ^ r8) * 8) * 2;

    floatx4 acc[4][2];
#pragma unroll
    for (int i = 0; i < 4; ++i)
#pragma unroll
        for (int j = 0; j < 2; ++j)
            acc[i][j] = (floatx4){0.f, 0.f, 0.f, 0.f};

#define STAGE_P(sp, ko)                                             \
    {                                                               \
        gload_lds16(gA0 + (ko), (sp) + dA0);                        \
        gload_lds16(gA1 + (ko), (sp) + dA1);                        \
        gload_lds16(gA2 + (ko), (sp) + dA2);                        \
    }
#define STAGE_Q(sp, ko)                                             \
    {                                                               \
        gload_lds16(gA3 + (ko), (sp) + dA3);                        \
        gload_lds16(gB0 + (ko), (sp) + dB0);                        \
        gload_lds16(gB1 + (ko), (sp) + dB1);                        \
    }
// One k-slice: 4 A + 2 B ds_read_b128, 8 MFMA.
#define PHASE(sb, aO, bO)                                           \
    {                                                               \
        const char* ab = (const char*)(sb) + (aO);                  \
        const char* bb = (const char*)(sb) + (bO);                  \
        bf16x8 a0 = *(const bf16x8*)(ab + 0 * 2048);                \
        bf16x8 a1 = *(const bf16x8*)(ab + 1 * 2048);                \
        bf16x8 a2 = *(const bf16x8*)(ab + 2 * 2048);                \
        bf16x8 a3 = *(const bf16x8*)(ab + 3 * 2048);                \
        bf16x8 b0 = *(const bf16x8*)(bb + 0 * 2048);                \
        bf16x8 b1 = *(const bf16x8*)(bb + 1 * 2048);                \
        bf16x8 av[4] = {a0, a1, a2, a3};                            \
        bf16x8 bv[2] = {b0, b1};                                    \
        __builtin_amdgcn_s_setprio(1);                              \
        _Pragma("unroll")                                           \
        for (int i = 0; i < 4; ++i)                                 \
            _Pragma("unroll")                                       \
            for (int j = 0; j < 2; ++j)                             \
                acc[i][j] = __builtin_amdgcn_mfma_f32_16x16x32_bf16(\
                    av[i], bv[j], acc[i][j], 0, 0, 0);              \
        __builtin_amdgcn_s_setprio(0);                              \
    }

    // ---- prologue: stage tiles 0 and 1, wait for tile 0 only ----
    {
        char* s0 = smem;
        char* s1 = smem + STG;
        STAGE_P(s0, 0); STAGE_Q(s0, 0);
        STAGE_P(s1, BK); STAGE_Q(s1, BK);
        WAIT_V6L0();       // tile 0 landed; tile 1's 6 loads in flight
        BARRIER();
    }

    int cur = 0;
    for (int kt = 0; kt < NT; ++kt) {
        char* sb = smem + cur * STG;
        int nx = cur + 2; if (nx >= 3) nx -= 3;
        char* sp = smem + nx * STG;
        const int kpre = (kt + 2) * BK;
        const bool pre = (kt < NT - 2);

        if (pre) STAGE_P(sp, kpre);
        PHASE(sb, aO0, bO0);           // k-slice 0
        if (pre) STAGE_Q(sp, kpre);
        PHASE(sb, aO1, bO1);           // k-slice 1

        if (pre) { WAIT_V6L0(); }      // tile kt+1 ready; kt+2 in flight
        else     { WAIT_V0L0(); }      // tail: drain
        BARRIER();
        ++cur; if (cur == 3) cur = 0;
    }
#undef PHASE
#undef STAGE_P
#undef STAGE_Q

    __syncthreads();   // full drain before LDS reuse as ebuf

    // ---- epilogue: dump 128x64 f32 via LDS (ES=68 pad), float4 out ----
    // D layout: col = t, row = q*4 + r  [m89/m91 verified]
#pragma unroll
    for (int tm = 0; tm < 4; ++tm)
#pragma unroll
        for (int tn = 0; tn < 2; ++tn)
#pragma unroll
            for (int r = 0; r < 4; ++r)
                ebuf[(wm * 64 + tm * 16 + q * 4 + r) * ES
                     + wn * 32 + tn * 16 + t] = acc[tm][tn][r];
    __syncthreads();
#pragma unroll
    for (int ps = 0; ps < 8; ++ps) {
        int row  = ps * 16 + (tid >> 4);
        int col4 = tid & 15;
        float4 v = *(const float4*)(ebuf + row * ES + col4 * 4);
        *(float4*)(C + (size_t)(bm * 128 + row) * OUTD + bn * 64 + col4 * 4) = v;
    }
}

extern "C" void kernel_launch(void* const* d_in, const int* in_sizes, int n_in,
                              void* d_out, int out_size, void* d_ws, size_t ws_size,
                              hipStream_t stream) {
    const float* x    = (const float*)d_in[0];
    const float* coef = (const float*)d_in[1];
    const float* w    = (const float*)d_in[2];
    float* out = (float*)d_out;

    unsigned short* xb   = (unsigned short*)d_ws;                                   // 16 MB
    unsigned short* weff = (unsigned short*)((char*)d_ws + (size_t)BATCH * IN * 2); // +2 MB

    prep_kernel<<<6144, 256, 0, stream>>>(x, coef, w, xb, weff);
    gemm_bt<<<dim3(BATCH / 128, OUTD / 64), 256, 0, stream>>>(xb, weff, out);
}